// Round 3
// baseline (1611.694 us; speedup 1.0000x reference)
//
#include <hip/hip_runtime.h>
#include <math.h>

#define KDIM 65536
#define MATF 262144           // 512*512 floats
#define EPSG 1e-6

using bf16x8 = __attribute__((ext_vector_type(8))) __bf16;
using f32x4  = __attribute__((ext_vector_type(4))) float;

// ---- ws layout ----
// 0      : unsigned bar_cnt (grid barrier, monotonic)
// 4096   : double S[16]   (0:n2A 1:n2B 2:trA 3:trB 4:cross)
// 4224   : float M[1024]  (means)
// 16384  : float G[2*MATF]                       (2 MB)
// 16384+2M: "big" region:
//          Gp[2*nk*MATF] split-K gram partials (nk=32 -> 64 MB; dead after gfin)
//          then reused for NS state (10 MB): Ya Yb Za Zb W (2 mats each)

__global__ __launch_bounds__(256) void k_means(const float* __restrict__ X,
                                               const float* __restrict__ Xt,
                                               float* __restrict__ M) {
  const int row = blockIdx.x, inp = blockIdx.y;
  const float4* p = (const float4*)((inp ? Xt : X) + (size_t)row * KDIM);
  double s = 0.0;
  for (int i = threadIdx.x; i < KDIM / 4; i += 256) {
    float4 v = p[i];
    s += (double)v.x + (double)v.y + (double)v.z + (double)v.w;
  }
  __shared__ double sm[256];
  sm[threadIdx.x] = s;
  __syncthreads();
  for (int o = 128; o > 0; o >>= 1) {
    if (threadIdx.x < o) sm[threadIdx.x] += sm[threadIdx.x + o];
    __syncthreads();
  }
  if (threadIdx.x == 0) M[inp * 512 + row] = (float)(sm[0] * (1.0 / KDIM));
}

__device__ __forceinline__ void cvt8(float4 a, float4 b, bf16x8& hi, bf16x8& lo) {
  float f[8] = {a.x, a.y, a.z, a.w, b.x, b.y, b.z, b.w};
#pragma unroll
  for (int e = 0; e < 8; ++e) {
    __bf16 h = (__bf16)f[e];
    hi[e] = h;
    lo[e] = (__bf16)(f[e] - (float)h);
  }
}

// k_gram: EXACT round-1 version (measured 228 us, passed). Raw X X^T partials
// via bf16 split-3 MFMA. 128x128 tiles (upper tri, 10), split-K nk chunks.
// grid (10, nk, 2), 256 threads. 1-deep register prefetch.
__global__ __launch_bounds__(256, 2) void k_gram(const float* __restrict__ X,
                                                 const float* __restrict__ Xt,
                                                 float* __restrict__ Gp, int nk) {
  int rem = blockIdx.x, ti = 0;
  while (rem >= 4 - ti) { rem -= 4 - ti; ++ti; }
  const int tj = ti + rem;
  const int chunk = blockIdx.y, inp = blockIdx.z;
  const int chunkv = KDIM / nk;
  const float* __restrict__ A = inp ? Xt : X;
  float* __restrict__ C = Gp + ((size_t)(inp * nk + chunk)) * MATF;
  const bool diag = (ti == tj);

  __shared__ bf16x8 AhV[512], AlV[512], BhV[512], BlV[512];   // 8 KB each

  const int t = threadIdx.x;
  const int srow = t & 127, skh = t >> 7;                 // stage row, k-half
  const int sbase = ((srow >> 4) << 6) + (skh << 5) + (srow & 15);

  const float* pa = A + (size_t)(ti * 128 + srow) * KDIM + (size_t)chunk * chunkv + skh * 16;
  const float* pb = A + (size_t)(tj * 128 + srow) * KDIM + (size_t)chunk * chunkv + skh * 16;

  const int wave = t >> 6, lane = t & 63;
  const int wy = (wave >> 1) * 64, wx = (wave & 1) * 64;

  f32x4 acc[4][4];
#pragma unroll
  for (int i = 0; i < 4; ++i)
#pragma unroll
    for (int j = 0; j < 4; ++j) acc[i][j] = (f32x4){0.f, 0.f, 0.f, 0.f};

  float4 ra0 = *(const float4*)(pa);
  float4 ra1 = *(const float4*)(pa + 4);
  float4 ra2 = *(const float4*)(pa + 8);
  float4 ra3 = *(const float4*)(pa + 12);
  float4 rb0 = {}, rb1 = {}, rb2 = {}, rb3 = {};
  if (!diag) {
    rb0 = *(const float4*)(pb);
    rb1 = *(const float4*)(pb + 4);
    rb2 = *(const float4*)(pb + 8);
    rb3 = *(const float4*)(pb + 12);
  }

  for (int ks = 0; ks < chunkv; ks += 32) {
    {
      bf16x8 h, l;
      cvt8(ra0, ra1, h, l); AhV[sbase] = h; AlV[sbase] = l;
      cvt8(ra2, ra3, h, l); AhV[sbase + 16] = h; AlV[sbase + 16] = l;
      if (!diag) {
        cvt8(rb0, rb1, h, l); BhV[sbase] = h; BlV[sbase] = l;
        cvt8(rb2, rb3, h, l); BhV[sbase + 16] = h; BlV[sbase + 16] = l;
      }
    }
    __syncthreads();
    if (ks + 32 < chunkv) {   // prefetch next step; overlaps with MFMA below
      ra0 = *(const float4*)(pa + ks + 32);
      ra1 = *(const float4*)(pa + ks + 36);
      ra2 = *(const float4*)(pa + ks + 40);
      ra3 = *(const float4*)(pa + ks + 44);
      if (!diag) {
        rb0 = *(const float4*)(pb + ks + 32);
        rb1 = *(const float4*)(pb + ks + 36);
        rb2 = *(const float4*)(pb + ks + 40);
        rb3 = *(const float4*)(pb + ks + 44);
      }
    }
    const bf16x8* __restrict__ Bh = diag ? AhV : BhV;
    const bf16x8* __restrict__ Bl = diag ? AlV : BlV;
    bf16x8 ah[4], al[4], bh[4], bl[4];
#pragma unroll
    for (int g = 0; g < 4; ++g) {
      ah[g] = AhV[((wave >> 1) * 4 + g) * 64 + lane];
      al[g] = AlV[((wave >> 1) * 4 + g) * 64 + lane];
      bh[g] = Bh[((wave & 1) * 4 + g) * 64 + lane];
      bl[g] = Bl[((wave & 1) * 4 + g) * 64 + lane];
    }
#pragma unroll
    for (int i = 0; i < 4; ++i)
#pragma unroll
      for (int j = 0; j < 4; ++j) {
        acc[i][j] = __builtin_amdgcn_mfma_f32_16x16x32_bf16(ah[i], bh[j], acc[i][j], 0, 0, 0);
        acc[i][j] = __builtin_amdgcn_mfma_f32_16x16x32_bf16(al[i], bh[j], acc[i][j], 0, 0, 0);
        acc[i][j] = __builtin_amdgcn_mfma_f32_16x16x32_bf16(ah[i], bl[j], acc[i][j], 0, 0, 0);
      }
    __syncthreads();
  }
  const int r4 = (lane >> 4) * 4, fc = lane & 15;
#pragma unroll
  for (int i = 0; i < 4; ++i) {
    const int grow = ti * 128 + wy + i * 16 + r4;
#pragma unroll
    for (int j = 0; j < 4; ++j) {
      const int gcol = tj * 128 + wx + j * 16 + fc;
#pragma unroll
      for (int r = 0; r < 4; ++r)
        C[(size_t)(grow + r) * 512 + gcol] = acc[i][j][r];
    }
  }
}

// ---------------------------------------------------------------------------
// Persistent tail kernel. Grid sized by the HOST from occupancy queries so
// co-residency is guaranteed; every phase is a grid-stride loop so any grid
// size >= 1 is correct. Spin has a 20 ms timeout: converts any residual
// deadlock into a wrong answer (diagnosable) instead of a container hang.
// ---------------------------------------------------------------------------
__device__ __forceinline__ void gbar(unsigned* cnt, unsigned target) {
  __syncthreads();
  if (threadIdx.x == 0) {
    __threadfence();                       // release: make block's writes visible
    atomicAdd(cnt, 1u);
    unsigned long long t0 = __builtin_amdgcn_s_memrealtime();
    while (__hip_atomic_load(cnt, __ATOMIC_RELAXED, __HIP_MEMORY_SCOPE_AGENT) < target) {
      __builtin_amdgcn_s_sleep(16);
      if (__builtin_amdgcn_s_memrealtime() - t0 > 2000000ull) break;  // ~20 ms
    }
    __threadfence();                       // acquire: discard stale cached data
  }
  __syncthreads();
}

__device__ __forceinline__ void tri8(int x, int& ti, int& tj) {
  int rem = x, i = 0;
  while (rem >= 8 - i) { rem -= 8 - i; ++i; }
  ti = i; tj = i + rem;
}

// 64x64-tile GEMM over K=512, bf16 split-3 MFMA. All NS matrices are
// symmetric polynomials in G, so A@B == A@B^T: both operands load ROW-wise
// (gram-style fragments, validated in round 1). Output symmetric: upper-tri
// tiles only, mirrored. 256 threads = 4 waves (2x2 of 32x32).
// mode 0: C = acc ; mode 1: C = 1.5*E - 0.5*acc
__device__ __forceinline__ void gemm64(const float* __restrict__ A,
                                       const float* __restrict__ B,
                                       const float* __restrict__ E,
                                       float* __restrict__ C,
                                       int ti, int tj, int mode,
                                       bf16x8* AhV, bf16x8* AlV,
                                       bf16x8* BhV, bf16x8* BlV) {
  const int t = threadIdx.x;
  const int srow = t & 63, sko = t >> 6;                  // stage row, k-octet
  const int sslot = ((srow >> 4) << 6) + (sko << 4) + (srow & 15);

  const float* pa = A + (size_t)(ti * 64 + srow) * 512 + sko * 8;
  const float* pb = B + (size_t)(tj * 64 + srow) * 512 + sko * 8;

  const int wave = t >> 6, lane = t & 63;
  const int wy = (wave >> 1) * 32, wx = (wave & 1) * 32;

  f32x4 acc[2][2];
#pragma unroll
  for (int i = 0; i < 2; ++i)
#pragma unroll
    for (int j = 0; j < 2; ++j) acc[i][j] = (f32x4){0.f, 0.f, 0.f, 0.f};

  float4 ra0 = *(const float4*)(pa), ra1 = *(const float4*)(pa + 4);
  float4 rb0 = *(const float4*)(pb), rb1 = *(const float4*)(pb + 4);

  for (int ks = 0; ks < 512; ks += 32) {
    {
      bf16x8 h, l;
      cvt8(ra0, ra1, h, l); AhV[sslot] = h; AlV[sslot] = l;
      cvt8(rb0, rb1, h, l); BhV[sslot] = h; BlV[sslot] = l;
    }
    __syncthreads();
    if (ks + 32 < 512) {   // prefetch next k-step
      ra0 = *(const float4*)(pa + ks + 32); ra1 = *(const float4*)(pa + ks + 36);
      rb0 = *(const float4*)(pb + ks + 32); rb1 = *(const float4*)(pb + ks + 36);
    }
    bf16x8 ah[2], al[2], bh[2], bl[2];
#pragma unroll
    for (int g = 0; g < 2; ++g) {
      ah[g] = AhV[((wy >> 4) + g) * 64 + lane];
      al[g] = AlV[((wy >> 4) + g) * 64 + lane];
      bh[g] = BhV[((wx >> 4) + g) * 64 + lane];
      bl[g] = BlV[((wx >> 4) + g) * 64 + lane];
    }
#pragma unroll
    for (int i = 0; i < 2; ++i)
#pragma unroll
      for (int j = 0; j < 2; ++j) {
        acc[i][j] = __builtin_amdgcn_mfma_f32_16x16x32_bf16(ah[i], bh[j], acc[i][j], 0, 0, 0);
        acc[i][j] = __builtin_amdgcn_mfma_f32_16x16x32_bf16(al[i], bh[j], acc[i][j], 0, 0, 0);
        acc[i][j] = __builtin_amdgcn_mfma_f32_16x16x32_bf16(ah[i], bl[j], acc[i][j], 0, 0, 0);
      }
    __syncthreads();
  }

  const int r4 = (lane >> 4) * 4, fc = lane & 15;
#pragma unroll
  for (int i = 0; i < 2; ++i) {
    const int grow = ti * 64 + wy + i * 16 + r4;
#pragma unroll
    for (int j = 0; j < 2; ++j) {
      const int gcol = tj * 64 + wx + j * 16 + fc;
      float v[4];
#pragma unroll
      for (int r = 0; r < 4; ++r) v[r] = acc[i][j][r];
      if (mode) {
#pragma unroll
        for (int r = 0; r < 4; ++r)
          v[r] = 1.5f * E[(size_t)(grow + r) * 512 + gcol] - 0.5f * v[r];
      }
#pragma unroll
      for (int r = 0; r < 4; ++r) C[(size_t)(grow + r) * 512 + gcol] = v[r];
      if (ti != tj) {   // mirror; grow%4==0 -> 16B aligned
        float4 mv = make_float4(v[0], v[1], v[2], v[3]);
        *(float4*)&C[(size_t)gcol * 512 + grow] = mv;
      }
    }
  }
}

__global__ __launch_bounds__(256, 2) void k_all(const float* Gp,       // == big (aliases): no restrict
                                                const float* __restrict__ M,
                                                float* __restrict__ Gm,
                                                double* __restrict__ S,
                                                unsigned* __restrict__ bar,
                                                float* big,
                                                float* __restrict__ out, int nk) {
  __shared__ bf16x8 AhV[256], AlV[256], BhV[256], BlV[256];   // 16 KB
  __shared__ double red[256];
  __shared__ float s_nrm[2];

  const int t = threadIdx.x;
  const int b = blockIdx.x;
  const int gsz = gridDim.x;
  unsigned tgt = 0;

  float* Ya = big;
  float* Yb = big + 2 * (size_t)MATF;
  float* Za = big + 4 * (size_t)MATF;
  float* Zb = big + 6 * (size_t)MATF;
  float* W  = big + 8 * (size_t)MATF;

  // ---- phase 0: gfin — reduce Gp partials, mean-correct, stats ----
  {
    double n2[2] = {0.0, 0.0}, trc[2] = {0.0, 0.0};
    for (int e = b * 256 + t; e < 2 * MATF; e += gsz * 256) {
      const int inp = e >> 18, idx = e & (MATF - 1);
      const int i = idx >> 9, j = idx & 511;
      if (i <= j) {
        double sum = 0.0;
        const float* p = Gp + (size_t)inp * nk * MATF + idx;
        for (int c = 0; c < nk; ++c) sum += (double)p[(size_t)c * MATF];
        sum -= 65536.0 * (double)M[inp * 512 + i] * (double)M[inp * 512 + j];
        if (i == j) sum += EPSG;
        float v = (float)(sum * (1.0 / 65536.0));
        Gm[e] = v;
        if (i < j) { Gm[((size_t)inp << 18) + j * 512 + i] = v; n2[inp] += 2.0 * (double)v * (double)v; }
        else       { n2[inp] += (double)v * (double)v; trc[inp] += (double)v; }
      }
    }
#pragma unroll
    for (int inp = 0; inp < 2; ++inp) {
      red[t] = n2[inp]; __syncthreads();
      for (int o = 128; o > 0; o >>= 1) { if (t < o) red[t] += red[t + o]; __syncthreads(); }
      if (t == 0) atomicAdd(&S[inp], red[0]);
      __syncthreads();
      red[t] = trc[inp]; __syncthreads();
      for (int o = 128; o > 0; o >>= 1) { if (t < o) red[t] += red[t + o]; __syncthreads(); }
      if (t == 0) atomicAdd(&S[2 + inp], red[0]);
      __syncthreads();
    }
  }
  gbar(bar, tgt += gsz);

  // ---- phase 1: init — Ya = G/norm ; Za = Z1 = 1.5I - 0.5*Y0 ----
  {
    if (t < 2)
      s_nrm[t] = (float)sqrt(__hip_atomic_load(&S[t], __ATOMIC_RELAXED, __HIP_MEMORY_SCOPE_AGENT));
    __syncthreads();
    for (int e = b * 256 + t; e < 2 * MATF; e += gsz * 256) {
      const int inp = e >> 18, idx = e & (MATF - 1);
      const float y = Gm[e] / s_nrm[inp];
      Ya[e] = y;
      Za[e] = ((idx >> 9) == (idx & 511)) ? (1.5f - 0.5f * y) : (-0.5f * y);
    }
  }
  gbar(bar, tgt += gsz);

  // ---- phase 2: first NS iter — Yb = 1.5*Y0 - 0.5*Y0@Y0 ----
  for (int job = b; job < 72; job += gsz) {
    const int mat = job >= 36;
    int ti, tj; tri8(job - mat * 36, ti, tj);
    const float* a = Ya + (size_t)mat * MATF;
    gemm64(a, a, a, Yb + (size_t)mat * MATF, ti, tj, 1, AhV, AlV, BhV, BlV);
  }
  gbar(bar, tgt += gsz);

  // ---- iterations 2..15 ----
  float *Y = Yb, *Z = Za, *Yn = Ya, *Zn = Zb;
  for (int it = 1; it < 15; ++it) {
    for (int job = b; job < 72; job += gsz) {       // W = Z@Y
      const int mat = job >= 36;
      int ti, tj; tri8(job - mat * 36, ti, tj);
      gemm64(Z + (size_t)mat * MATF, Y + (size_t)mat * MATF, nullptr,
             W + (size_t)mat * MATF, ti, tj, 0, AhV, AlV, BhV, BlV);
    }
    gbar(bar, tgt += gsz);
    for (int job = b; job < 144; job += gsz) {
      if (job < 72) {                               // Yn = 1.5Y - 0.5*Y@W
        const int mat = job >= 36;
        int ti, tj; tri8(job - mat * 36, ti, tj);
        gemm64(Y + (size_t)mat * MATF, W + (size_t)mat * MATF, Y + (size_t)mat * MATF,
               Yn + (size_t)mat * MATF, ti, tj, 1, AhV, AlV, BhV, BlV);
      } else {                                      // Zn = 1.5Z - 0.5*W@Z
        const int jb = job - 72;
        const int mat = jb >= 36;
        int ti, tj; tri8(jb - mat * 36, ti, tj);
        gemm64(W + (size_t)mat * MATF, Z + (size_t)mat * MATF, Z + (size_t)mat * MATF,
               Zn + (size_t)mat * MATF, ti, tj, 1, AhV, AlV, BhV, BlV);
      }
    }
    gbar(bar, tgt += gsz);
    float* tmp;
    tmp = Y; Y = Yn; Yn = tmp;
    tmp = Z; Z = Zn; Zn = tmp;
  }

  // ---- cross: sum_ij YA[i,j]*YB[j,i] ----
  {
    double s = 0.0;
    for (int id = b * 256 + t; id < MATF; id += gsz * 256) {
      const int i = id >> 9, j = id & 511;
      s += (double)Y[id] * (double)Y[MATF + j * 512 + i];
    }
    red[t] = s;
    __syncthreads();
    for (int o = 128; o > 0; o >>= 1) {
      if (t < o) red[t] += red[t + o];
      __syncthreads();
    }
    if (t == 0) atomicAdd(&S[4], red[0]);
  }
  gbar(bar, tgt += gsz);

  // ---- final: block 0 combines ----
  if (b == 0) {
    double s = 0.0;
    for (int i = t; i < 512; i += 256) {
      double d = (double)M[i] - (double)M[512 + i];
      s += d * d;
    }
    red[t] = s;
    __syncthreads();
    for (int o = 128; o > 0; o >>= 1) {
      if (t < o) red[t] += red[t + o];
      __syncthreads();
    }
    if (t == 0) {
      double s0 = __hip_atomic_load(&S[0], __ATOMIC_RELAXED, __HIP_MEMORY_SCOPE_AGENT);
      double s1 = __hip_atomic_load(&S[1], __ATOMIC_RELAXED, __HIP_MEMORY_SCOPE_AGENT);
      double s2 = __hip_atomic_load(&S[2], __ATOMIC_RELAXED, __HIP_MEMORY_SCOPE_AGENT);
      double s3 = __hip_atomic_load(&S[3], __ATOMIC_RELAXED, __HIP_MEMORY_SCOPE_AGENT);
      double s4 = __hip_atomic_load(&S[4], __ATOMIC_RELAXED, __HIP_MEMORY_SCOPE_AGENT);
      double scale = sqrt(sqrt(s0) * sqrt(s1));
      double loss = red[0] + s2 + s3 - 2.0 * scale * s4;
      out[0] = (float)(loss / 512.0);
    }
  }
}

extern "C" void kernel_launch(void* const* d_in, const int* in_sizes, int n_in,
                              void* d_out, int out_size, void* d_ws, size_t ws_size,
                              hipStream_t stream) {
  const float* X = (const float*)d_in[0];
  const float* Xt = (const float*)d_in[1];
  char* wsb = (char*)d_ws;
  unsigned* bar = (unsigned*)wsb;
  double* S = (double*)(wsb + 4096);
  float* Mv = (float*)(wsb + 4224);
  float* G = (float*)(wsb + 16384);
  float* big = (float*)(wsb + 16384 + 2 * (size_t)MATF * 4);

  // split-K factor for the gram: 32 if the workspace can hold the partials
  const size_t need32 = 16384 + 2 * (size_t)MATF * 4 + 2 * 32 * (size_t)MATF * 4;
  const int nk = (ws_size >= need32) ? 32 : 16;

  // Persistent-kernel grid: guaranteed-co-resident block count from occupancy
  // (host-side queries only — safe under graph capture). Cap at 256.
  static int s_grid = 0;
  if (s_grid == 0) {
    int dev = 0;
    hipGetDevice(&dev);
    int ncu = 0;
    hipDeviceGetAttribute(&ncu, hipDeviceAttributeMultiprocessorCount, dev);
    int maxb = 0;
    hipOccupancyMaxActiveBlocksPerMultiprocessor(&maxb, k_all, 256, 0);
    if (ncu <= 0) ncu = 64;
    if (maxb <= 0) maxb = 1;
    long cap = (long)ncu * maxb;
    s_grid = (cap < 256) ? (int)cap : 256;
    if (s_grid < 1) s_grid = 1;
  }

  hipMemsetAsync(wsb, 0, 4224, stream);   // bar + S
  k_means<<<dim3(512, 2), 256, 0, stream>>>(X, Xt, Mv);
  k_gram<<<dim3(10, nk, 2), 256, 0, stream>>>(X, Xt, big, nk);
  k_all<<<dim3(s_grid), 256, 0, stream>>>(big, Mv, G, S, bar, big,
                                          (float*)d_out, nk);
}